// Round 1
// 2640.895 us; speedup vs baseline: 1.1406x; 1.1406x over previous
//
#include <hip/hip_runtime.h>
#include <cstddef>

typedef __bf16 v8bf __attribute__((ext_vector_type(8)));
typedef __bf16 v4bf __attribute__((ext_vector_type(4)));
typedef float  v4f  __attribute__((ext_vector_type(4)));

#define S_LEN 2048
#define D_DIM 4096
#define NH    32
#define NKV   8
#define HD    128

__device__ inline v4f mfma16(v8bf a, v8bf b, v4f c) {
    return __builtin_amdgcn_mfma_f32_16x16x32_bf16(a, b, c, 0, 0, 0);
}

// ---------------- RMSNorm (fp32 in, bf16 out), one block per row ----------------
__global__ __launch_bounds__(256) void rmsnorm_bf16(
    const float* __restrict__ x, const float* __restrict__ w, __bf16* __restrict__ out)
{
    const int D = D_DIM;
    int row = blockIdx.x;
    const float4* xr = (const float4*)(x + (size_t)row * D);
    const float4* wr = (const float4*)w;
    int tid = threadIdx.x;
    float4 v[4];
    float ss = 0.f;
#pragma unroll
    for (int i = 0; i < 4; i++) {
        v[i] = xr[tid + i * 256];
        ss += v[i].x * v[i].x + v[i].y * v[i].y + v[i].z * v[i].z + v[i].w * v[i].w;
    }
#pragma unroll
    for (int off = 32; off; off >>= 1) ss += __shfl_xor(ss, off);
    __shared__ float red[4];
    if ((tid & 63) == 0) red[tid >> 6] = ss;
    __syncthreads();
    ss = red[0] + red[1] + red[2] + red[3];
    float rs = rsqrtf(ss * (1.f / D) + 1e-5f);
#pragma unroll
    for (int i = 0; i < 4; i++) {
        float4 ww = wr[tid + i * 256];
        v4bf t;
        t[0] = (__bf16)(v[i].x * rs * ww.x);
        t[1] = (__bf16)(v[i].y * rs * ww.y);
        t[2] = (__bf16)(v[i].z * rs * ww.z);
        t[3] = (__bf16)(v[i].w * rs * ww.w);
        *(v4bf*)&out[(size_t)row * D + (size_t)(tid + i * 256) * 4] = t;
    }
}

// ---------------- GEMM: C[M,N] = A[M,K](bf16) @ W[N,K]^T(f32->bf16) (+bias)(+res) ----------------
// 128x128 tile, 4 waves, each wave 64x64 via 4x4 MFMA 16x16x32.
template <typename OutT, bool HAS_BIAS, bool HAS_RES>
__global__ __launch_bounds__(256) void gemm_bt(
    const __bf16* __restrict__ A, const float* __restrict__ W,
    const float* __restrict__ bias, const float* res, OutT* C, int N, int K)
{
    constexpr int BK = 64;
    __shared__ __align__(16) __bf16 As[128 * BK];
    __shared__ __align__(16) __bf16 Ws[128 * BK];
    int m0 = blockIdx.y * 128, n0 = blockIdx.x * 128;
    int tid = threadIdx.x;
    int w = tid >> 6, l = tid & 63, g = l >> 4, c = l & 15;
    int wm = (w >> 1) * 64, wn = (w & 1) * 64;
    v4f zero = {0.f, 0.f, 0.f, 0.f};
    v4f acc[4][4];
#pragma unroll
    for (int i = 0; i < 4; i++)
#pragma unroll
        for (int j = 0; j < 4; j++) acc[i][j] = zero;

    for (int k0 = 0; k0 < K; k0 += BK) {
        __syncthreads();
#pragma unroll
        for (int i = 0; i < 4; i++) {  // A: 128x64 bf16 = 1024 chunks of 8
            int ch = tid + i * 256;
            int r = ch >> 3, c8 = ch & 7;
            *(uint4*)&As[r * BK + c8 * 8] =
                *(const uint4*)&A[(size_t)(m0 + r) * K + k0 + c8 * 8];
        }
#pragma unroll
        for (int i = 0; i < 8; i++) {  // W: 128x64 f32 = 2048 float4 chunks
            int ch = tid + i * 256;
            int r = ch >> 4, c4 = ch & 15;
            float4 f = *(const float4*)&W[(size_t)(n0 + r) * K + k0 + c4 * 4];
            v4bf t;
            t[0] = (__bf16)f.x; t[1] = (__bf16)f.y; t[2] = (__bf16)f.z; t[3] = (__bf16)f.w;
            *(v4bf*)&Ws[r * BK + c4 * 4] = t;
        }
        __syncthreads();
#pragma unroll
        for (int kk = 0; kk < BK; kk += 32) {
            v8bf af[4], wf[4];
#pragma unroll
            for (int i = 0; i < 4; i++) af[i] = *(const v8bf*)&As[(wm + i * 16 + c) * BK + kk + g * 8];
#pragma unroll
            for (int j = 0; j < 4; j++) wf[j] = *(const v8bf*)&Ws[(wn + j * 16 + c) * BK + kk + g * 8];
#pragma unroll
            for (int i = 0; i < 4; i++)
#pragma unroll
                for (int j = 0; j < 4; j++) acc[i][j] = mfma16(af[i], wf[j], acc[i][j]);
        }
    }
    // epilogue: C/D layout col=lane&15, row=quad*4+reg
#pragma unroll
    for (int i = 0; i < 4; i++)
#pragma unroll
        for (int j = 0; j < 4; j++) {
            int mm = m0 + wm + i * 16 + g * 4;
            int nn = n0 + wn + j * 16 + c;
#pragma unroll
            for (int r = 0; r < 4; r++) {
                float vv = acc[i][j][r];
                if (HAS_BIAS) vv += bias[nn];
                if (HAS_RES) vv += res[(size_t)(mm + r) * N + nn];
                C[(size_t)(mm + r) * N + nn] = (OutT)vv;
            }
        }
}

// ---------------- RoPE in-place on bf16 Q [S][NH][HD] and K [S][NKV][HD] ----------------
__global__ __launch_bounds__(256) void rope_inplace(
    __bf16* Q, __bf16* K, const int* __restrict__ sidx)
{
    int s = blockIdx.x;
    float p = (float)sidx[s];
    for (int t = threadIdx.x; t < (NH + NKV) * 64; t += 256) {
        int head = t >> 6, d = t & 63;
        float inv = __expf(-0.2158673520f * (float)d);  // ln(1e6)/64
        float sn, cs;
        sincosf(p * inv, &sn, &cs);
        __bf16* base;
        if (head < NH) base = Q + ((size_t)s * NH + head) * HD + d;
        else           base = K + ((size_t)s * NKV + (head - NH)) * HD + d;
        float x1 = (float)base[0], x2 = (float)base[64];
        base[0]  = (__bf16)(x1 * cs - x2 * sn);
        base[64] = (__bf16)(x2 * cs + x1 * sn);
    }
}

// ---------------- Flash attention, causal GQA ----------------
// grid (S/128, NH): each block processes TWO q-tiles (qt and NQT-1-qt) so per-block
// work is uniform (66 key-tiles) despite the causal triangle.
// 4 waves; wave w handles rows q0+16w..+15; 32-key tiles.
// LDS swizzles: Ks column-chunk XOR (kills the 16-way conflict on QK B-fragment
// reads), Vt pitch-64 + feat-derived XOR (kills 16-way transpose-write conflict
// while keeping B-fragment reads bank-uniform), Pl padded to 40.
__device__ inline int kswz(int key, int col8) {
    return key * 128 + (col8 ^ ((key & 7) << 3));
}
__device__ inline int vswz(int feat) {
    return ((feat ^ (feat >> 3)) & 7) << 3;
}

__global__ __launch_bounds__(256) void flash_attn(
    const __bf16* __restrict__ Q, const __bf16* __restrict__ K,
    const __bf16* __restrict__ V, __bf16* __restrict__ O)
{
    const float scale = 0.08838834764831845f;  // 1/sqrt(128)
    const int NQT = S_LEN / 64;
    int bx = blockIdx.x, h = blockIdx.y;
    int kvh = h >> 2;
    int tid = threadIdx.x;
    int w = tid >> 6, l = tid & 63, g = l >> 4, c = l & 15;

    __shared__ __align__(16) __bf16 Ks[32 * 128];
    __shared__ __align__(16) __bf16 Vt[128 * 64];
    __shared__ __align__(16) __bf16 Pl[4][16][40];

    for (int pass = 0; pass < 2; ++pass) {
        int qt = pass ? (NQT - 1 - bx) : bx;
        int q0 = qt * 64;
        int rowbase = q0 + w * 16;

        v8bf qf[4];
#pragma unroll
        for (int kk = 0; kk < 4; kk++)
            qf[kk] = *(const v8bf*)&Q[((size_t)(rowbase + c) * NH + h) * HD + kk * 32 + g * 8];

        float m_r[4], l_r[4], alpha[4];
        v4f zero = {0.f, 0.f, 0.f, 0.f};
        v4f o[8];
#pragma unroll
        for (int f = 0; f < 8; f++) o[f] = zero;
#pragma unroll
        for (int r = 0; r < 4; r++) { m_r[r] = -1e30f; l_r[r] = 0.f; }

        int ntiles = 2 * qt + 2;
        for (int t = 0; t < ntiles; t++) {
            int j0 = t * 32;
            __syncthreads();
#pragma unroll
            for (int i = 0; i < 2; i++) {  // stage 32 keys x 128 feats
                int ch = tid + i * 256;
                int key = ch >> 4, f8 = ch & 15;
                size_t gidx = ((size_t)(j0 + key) * NKV + kvh) * HD + f8 * 8;
                *(uint4*)&Ks[kswz(key, f8 * 8)] = *(const uint4*)&K[gidx];
                v8bf vv = *(const v8bf*)&V[gidx];
#pragma unroll
                for (int j = 0; j < 8; j++) {
                    int feat = f8 * 8 + j;
                    Vt[feat * 64 + (key ^ vswz(feat))] = vv[j];
                }
            }
            __syncthreads();
            v4f s0 = zero, s1 = zero;
            __builtin_amdgcn_s_setprio(1);
#pragma unroll
            for (int kk = 0; kk < 4; kk++) {
                v8bf k0f = *(const v8bf*)&Ks[kswz(c, kk * 32 + g * 8)];
                v8bf k1f = *(const v8bf*)&Ks[kswz(16 + c, kk * 32 + g * 8)];
                s0 = mfma16(qf[kk], k0f, s0);
                s1 = mfma16(qf[kk], k1f, s1);
            }
            __builtin_amdgcn_s_setprio(0);
            float p0[4], p1[4];
#pragma unroll
            for (int r = 0; r < 4; r++) {
                int row = rowbase + g * 4 + r;
                float a = s0[r] * scale, b = s1[r] * scale;
                if (j0 + c > row) a = -1e30f;
                if (j0 + 16 + c > row) b = -1e30f;
                float v = fmaxf(a, b);
                v = fmaxf(v, __shfl_xor(v, 1));
                v = fmaxf(v, __shfl_xor(v, 2));
                v = fmaxf(v, __shfl_xor(v, 4));
                v = fmaxf(v, __shfl_xor(v, 8));
                float mn = fmaxf(m_r[r], v);
                float al = __expf(m_r[r] - mn);
                float e0 = __expf(a - mn), e1 = __expf(b - mn);
                float srow = e0 + e1;
                srow += __shfl_xor(srow, 1);
                srow += __shfl_xor(srow, 2);
                srow += __shfl_xor(srow, 4);
                srow += __shfl_xor(srow, 8);
                l_r[r] = al * l_r[r] + srow;
                m_r[r] = mn;
                alpha[r] = al;
                p0[r] = e0; p1[r] = e1;
            }
#pragma unroll
            for (int f = 0; f < 8; f++)
#pragma unroll
                for (int r = 0; r < 4; r++) o[f][r] *= alpha[r];
            // P (C-layout) -> LDS -> A-layout
#pragma unroll
            for (int r = 0; r < 4; r++) {
                Pl[w][g * 4 + r][c] = (__bf16)p0[r];
                Pl[w][g * 4 + r][16 + c] = (__bf16)p1[r];
            }
            __syncthreads();
            v8bf pf = *(const v8bf*)&Pl[w][c][g * 8];
            __builtin_amdgcn_s_setprio(1);
#pragma unroll
            for (int f = 0; f < 8; f++) {
                int feat = f * 16 + c;
                v8bf vf = *(const v8bf*)&Vt[feat * 64 + ((g * 8) ^ vswz(feat))];
                o[f] = mfma16(pf, vf, o[f]);
            }
            __builtin_amdgcn_s_setprio(0);
        }
#pragma unroll
        for (int f = 0; f < 8; f++)
#pragma unroll
            for (int r = 0; r < 4; r++) {
                float val = o[f][r] / l_r[r];
                O[((size_t)(rowbase + g * 4 + r) * NH + h) * HD + f * 16 + c] = (__bf16)val;
            }
    }
}

// ---------------- SwiGLU elementwise: mid = silu(gate) * up ----------------
__global__ __launch_bounds__(256) void silu_mul(
    const __bf16* __restrict__ g, const __bf16* __restrict__ u, __bf16* __restrict__ out)
{
    size_t i = ((size_t)blockIdx.x * 256 + threadIdx.x) * 8;
    v8bf gv = *(const v8bf*)&g[i];
    v8bf uv = *(const v8bf*)&u[i];
    v8bf ov;
#pragma unroll
    for (int j = 0; j < 8; j++) {
        float x = (float)gv[j];
        float s = x / (1.f + __expf(-x));
        ov[j] = (__bf16)(s * (float)uv[j]);
    }
    *(v8bf*)&out[i] = ov;
}

extern "C" void kernel_launch(void* const* d_in, const int* in_sizes, int n_in,
                              void* d_out, int out_size, void* d_ws, size_t ws_size,
                              hipStream_t stream)
{
    const float* x   = (const float*)d_in[0];
    const float* wq  = (const float*)d_in[2];
    const float* bq  = (const float*)d_in[3];
    const float* wk  = (const float*)d_in[4];
    const float* bk  = (const float*)d_in[5];
    const float* wv  = (const float*)d_in[6];
    const float* bv  = (const float*)d_in[7];
    const float* wo  = (const float*)d_in[8];
    const float* wg  = (const float*)d_in[9];
    const float* wu  = (const float*)d_in[10];
    const float* wd  = (const float*)d_in[11];
    const float* ln1 = (const float*)d_in[12];
    const float* ln2 = (const float*)d_in[13];
    const int* sidx  = (const int*)d_in[14];
    float* out = (float*)d_out;

    char* ws = (char*)d_ws;
    const size_t MB = 1u << 20;
    __bf16* h_in = (__bf16*)(ws + 0 * MB);    // 16 MB
    __bf16* q_b  = (__bf16*)(ws + 16 * MB);   // 16 MB
    __bf16* k_b  = (__bf16*)(ws + 32 * MB);   // 4 MB
    __bf16* v_b  = (__bf16*)(ws + 36 * MB);   // 4 MB
    __bf16* ao   = (__bf16*)(ws + 40 * MB);   // 16 MB
    __bf16* h2   = (__bf16*)(ws + 56 * MB);   // 16 MB
    __bf16* gate = (__bf16*)(ws + 72 * MB);   // 56 MB
    __bf16* up   = (__bf16*)(ws + 128 * MB);  // 56 MB
    __bf16* mid  = (__bf16*)(ws + 184 * MB);  // 56 MB -> 240 MB total

    // 1) h_in = rmsnorm(x, ln1) in bf16
    rmsnorm_bf16<<<S_LEN, 256, 0, stream>>>(x, ln1, h_in);
    // 2-4) QKV projections (+bias), bf16 out
    gemm_bt<__bf16, true, false><<<dim3(32, 16), 256, 0, stream>>>(h_in, wq, bq, nullptr, q_b, 4096, 4096);
    gemm_bt<__bf16, true, false><<<dim3(8, 16), 256, 0, stream>>>(h_in, wk, bk, nullptr, k_b, 1024, 4096);
    gemm_bt<__bf16, true, false><<<dim3(8, 16), 256, 0, stream>>>(h_in, wv, bv, nullptr, v_b, 1024, 4096);
    // 5) RoPE in place
    rope_inplace<<<S_LEN, 256, 0, stream>>>(q_b, k_b, sidx);
    // 6) causal GQA flash attention (paired q-tiles for causal load balance)
    flash_attn<<<dim3(S_LEN / 128, NH), 256, 0, stream>>>(q_b, k_b, v_b, ao);
    // 7) r = x + ao @ wo^T  -> d_out (fp32)
    gemm_bt<float, false, true><<<dim3(32, 16), 256, 0, stream>>>(ao, wo, nullptr, x, out, 4096, 4096);
    // 8) h2 = rmsnorm(r, ln2) bf16
    rmsnorm_bf16<<<S_LEN, 256, 0, stream>>>(out, ln2, h2);
    // 9-10) gate/up projections
    gemm_bt<__bf16, false, false><<<dim3(112, 16), 256, 0, stream>>>(h2, wg, nullptr, nullptr, gate, 14336, 4096);
    gemm_bt<__bf16, false, false><<<dim3(112, 16), 256, 0, stream>>>(h2, wu, nullptr, nullptr, up, 14336, 4096);
    // 11) mid = silu(gate)*up
    silu_mul<<<(S_LEN * 14336) / (256 * 8), 256, 0, stream>>>(gate, up, mid);
    // 12) out = r + mid @ wd^T (residual read from d_out, in-place)
    gemm_bt<float, false, true><<<dim3(32, 16), 256, 0, stream>>>(mid, wd, nullptr, out, out, 4096, 14336);
}

// Round 2
// 2304.912 us; speedup vs baseline: 1.3068x; 1.1458x over previous
//
#include <hip/hip_runtime.h>
#include <cstddef>

typedef __bf16 v8bf __attribute__((ext_vector_type(8)));
typedef __bf16 v4bf __attribute__((ext_vector_type(4)));
typedef float  v4f  __attribute__((ext_vector_type(4)));

#define S_LEN 2048
#define D_DIM 4096
#define NH    32
#define NKV   8
#define HD    128

__device__ inline v4f mfma16(v8bf a, v8bf b, v4f c) {
    return __builtin_amdgcn_mfma_f32_16x16x32_bf16(a, b, c, 0, 0, 0);
}

// async global->LDS, 16B per lane. LDS dest is wave-uniform base + lane*16
// (we pass per-lane ptrs that equal exactly that), global src is per-lane.
__device__ inline void gload16(const void* g, void* l) {
    __builtin_amdgcn_global_load_lds(
        (const __attribute__((address_space(1))) void*)g,
        (__attribute__((address_space(3))) void*)l, 16, 0, 0);
}

// ---------------- fp32 -> bf16 weight conversion (pure BW) ----------------
__global__ __launch_bounds__(256) void f32_to_bf16(
    const float* __restrict__ src, __bf16* __restrict__ dst, int n4)
{
    int stride = gridDim.x * 256;
    for (int i = blockIdx.x * 256 + threadIdx.x; i < n4; i += stride) {
        float4 f = ((const float4*)src)[i];
        v4bf t;
        t[0] = (__bf16)f.x; t[1] = (__bf16)f.y; t[2] = (__bf16)f.z; t[3] = (__bf16)f.w;
        ((v4bf*)dst)[i] = t;
    }
}

// ---------------- RMSNorm (fp32 in, bf16 out), one block per row ----------------
__global__ __launch_bounds__(256) void rmsnorm_bf16(
    const float* __restrict__ x, const float* __restrict__ w, __bf16* __restrict__ out)
{
    const int D = D_DIM;
    int row = blockIdx.x;
    const float4* xr = (const float4*)(x + (size_t)row * D);
    const float4* wr = (const float4*)w;
    int tid = threadIdx.x;
    float4 v[4];
    float ss = 0.f;
#pragma unroll
    for (int i = 0; i < 4; i++) {
        v[i] = xr[tid + i * 256];
        ss += v[i].x * v[i].x + v[i].y * v[i].y + v[i].z * v[i].z + v[i].w * v[i].w;
    }
#pragma unroll
    for (int off = 32; off; off >>= 1) ss += __shfl_xor(ss, off);
    __shared__ float red[4];
    if ((tid & 63) == 0) red[tid >> 6] = ss;
    __syncthreads();
    ss = red[0] + red[1] + red[2] + red[3];
    float rs = rsqrtf(ss * (1.f / D) + 1e-5f);
#pragma unroll
    for (int i = 0; i < 4; i++) {
        float4 ww = wr[tid + i * 256];
        v4bf t;
        t[0] = (__bf16)(v[i].x * rs * ww.x);
        t[1] = (__bf16)(v[i].y * rs * ww.y);
        t[2] = (__bf16)(v[i].z * rs * ww.z);
        t[3] = (__bf16)(v[i].w * rs * ww.w);
        *(v4bf*)&out[(size_t)row * D + (size_t)(tid + i * 256) * 4] = t;
    }
}

// ---------------- GEMM: C[M,N] = A[M,K](bf16) @ W[N,K]^T (+bias)(+res)(+glu) ----------------
// 128x128 tile, BK=64, 4 waves. m97 structure: global_load_lds dwordx4 staging,
// XOR-swizzled LDS (16B chunk ^= row&7): source pre-swizzle + swizzled reads
// (both-sides rule). 2-way max bank aliasing on fragment reads (free).
// W_BF16=false fallback: reg-staged fp32 W with swizzled ds_write (same read swz).
template <typename OutT, bool W_BF16, bool HAS_BIAS, bool HAS_RES, bool HAS_GLU>
__global__ __launch_bounds__(256) void gemm_bt(
    const __bf16* __restrict__ A, const void* __restrict__ Wp,
    const float* __restrict__ bias, const float* __restrict__ res,
    const __bf16* __restrict__ glu, OutT* __restrict__ C, int N, int K)
{
    constexpr int BK = 64;
    __shared__ __align__(16) __bf16 As[128 * BK];
    __shared__ __align__(16) __bf16 Ws[128 * BK];

    // XCD-aware bijective swizzle (all launch grids have nwg % 8 == 0)
    int nwg = gridDim.x * gridDim.y;
    int bid = blockIdx.y * gridDim.x + blockIdx.x;
    int cpx = nwg >> 3;
    int sbid = (bid & 7) * cpx + (bid >> 3);
    int m0 = (sbid / gridDim.x) * 128, n0 = (sbid % gridDim.x) * 128;

    int tid = threadIdx.x;
    int w = tid >> 6, l = tid & 63, g = l >> 4, c = l & 15;
    int wm = (w >> 1) * 64, wn = (w & 1) * 64;

    // staging decomposition: 32 rows x 8 chunks(16B) per iter
    int srow = tid >> 3;          // 0..31
    int sj   = tid & 7;           // LDS 16B-chunk index within row
    int sjj  = sj ^ (srow & 7);   // swizzled global chunk

    v4f zero = {0.f, 0.f, 0.f, 0.f};
    v4f acc[4][4];
#pragma unroll
    for (int i = 0; i < 4; i++)
#pragma unroll
        for (int j = 0; j < 4; j++) acc[i][j] = zero;

    for (int k0 = 0; k0 < K; k0 += BK) {
        __syncthreads();
        // A: 128x64 bf16, 4 iters of 32 rows; LDS linear, source pre-swizzled
#pragma unroll
        for (int i = 0; i < 4; i++) {
            int r = i * 32 + srow;
            gload16(&A[(size_t)(m0 + r) * K + k0 + sjj * 8],
                    (char*)As + r * 128 + sj * 16);
        }
        if (W_BF16) {
            const __bf16* W = (const __bf16*)Wp;
#pragma unroll
            for (int i = 0; i < 4; i++) {
                int r = i * 32 + srow;
                gload16(&W[(size_t)(n0 + r) * K + k0 + sjj * 8],
                        (char*)Ws + r * 128 + sj * 16);
            }
        } else {
            const float* W = (const float*)Wp;
#pragma unroll
            for (int i = 0; i < 8; i++) {
                int ch = tid + i * 256;
                int r = ch >> 4, c4 = ch & 15;  // 8B chunk c4
                float4 f = *(const float4*)&W[(size_t)(n0 + r) * K + k0 + c4 * 4];
                v4bf t;
                t[0] = (__bf16)f.x; t[1] = (__bf16)f.y; t[2] = (__bf16)f.z; t[3] = (__bf16)f.w;
                int phys = r * 128 + (((c4 >> 1) ^ (r & 7)) << 4) + ((c4 & 1) << 3);
                *(v4bf*)((char*)Ws + phys) = t;
            }
        }
        __syncthreads();
#pragma unroll
        for (int kk = 0; kk < BK; kk += 32) {
            int jb = kk >> 3;  // base 16B-chunk: 0 or 4
            v8bf af[4], wf[4];
#pragma unroll
            for (int i = 0; i < 4; i++) {
                int row = wm + i * 16 + c;
                af[i] = *(const v8bf*)((char*)As + row * 128 + (((jb + g) ^ (c & 7)) << 4));
            }
#pragma unroll
            for (int j = 0; j < 4; j++) {
                int row = wn + j * 16 + c;
                wf[j] = *(const v8bf*)((char*)Ws + row * 128 + (((jb + g) ^ (c & 7)) << 4));
            }
#pragma unroll
            for (int i = 0; i < 4; i++)
#pragma unroll
                for (int j = 0; j < 4; j++) acc[i][j] = mfma16(af[i], wf[j], acc[i][j]);
        }
    }
    // epilogue: C/D layout col=lane&15, row=quad*4+reg
#pragma unroll
    for (int i = 0; i < 4; i++)
#pragma unroll
        for (int j = 0; j < 4; j++) {
            int mm = m0 + wm + i * 16 + g * 4;
            int nn = n0 + wn + j * 16 + c;
#pragma unroll
            for (int r = 0; r < 4; r++) {
                float vv = acc[i][j][r];
                if (HAS_BIAS) vv += bias[nn];
                if (HAS_RES) vv += res[(size_t)(mm + r) * N + nn];
                if (HAS_GLU) {
                    float gx = (float)glu[(size_t)(mm + r) * N + nn];
                    vv *= gx / (1.f + __expf(-gx));
                }
                C[(size_t)(mm + r) * N + nn] = (OutT)vv;
            }
        }
}

// ---------------- RoPE in-place on bf16 Q [S][NH][HD] and K [S][NKV][HD] ----------------
__global__ __launch_bounds__(256) void rope_inplace(
    __bf16* Q, __bf16* K, const int* __restrict__ sidx)
{
    int s = blockIdx.x;
    float p = (float)sidx[s];
    for (int t = threadIdx.x; t < (NH + NKV) * 64; t += 256) {
        int head = t >> 6, d = t & 63;
        float inv = __expf(-0.2158673520f * (float)d);  // ln(1e6)/64
        float sn, cs;
        sincosf(p * inv, &sn, &cs);
        __bf16* base;
        if (head < NH) base = Q + ((size_t)s * NH + head) * HD + d;
        else           base = K + ((size_t)s * NKV + (head - NH)) * HD + d;
        float x1 = (float)base[0], x2 = (float)base[64];
        base[0]  = (__bf16)(x1 * cs - x2 * sn);
        base[64] = (__bf16)(x2 * cs + x1 * sn);
    }
}

// ---------------- Flash attention, causal GQA (paired q-tiles, swizzled LDS) ----------------
__device__ inline int kswz(int key, int col8) {
    return key * 128 + (col8 ^ ((key & 7) << 3));
}
__device__ inline int vswz(int feat) {
    return ((feat ^ (feat >> 3)) & 7) << 3;
}

__global__ __launch_bounds__(256) void flash_attn(
    const __bf16* __restrict__ Q, const __bf16* __restrict__ K,
    const __bf16* __restrict__ V, __bf16* __restrict__ O)
{
    const float scale = 0.08838834764831845f;  // 1/sqrt(128)
    const int NQT = S_LEN / 64;
    int bx = blockIdx.x, h = blockIdx.y;
    int kvh = h >> 2;
    int tid = threadIdx.x;
    int w = tid >> 6, l = tid & 63, g = l >> 4, c = l & 15;

    __shared__ __align__(16) __bf16 Ks[32 * 128];
    __shared__ __align__(16) __bf16 Vt[128 * 64];
    __shared__ __align__(16) __bf16 Pl[4][16][40];

    for (int pass = 0; pass < 2; ++pass) {
        int qt = pass ? (NQT - 1 - bx) : bx;
        int q0 = qt * 64;
        int rowbase = q0 + w * 16;

        v8bf qf[4];
#pragma unroll
        for (int kk = 0; kk < 4; kk++)
            qf[kk] = *(const v8bf*)&Q[((size_t)(rowbase + c) * NH + h) * HD + kk * 32 + g * 8];

        float m_r[4], l_r[4], alpha[4];
        v4f zero = {0.f, 0.f, 0.f, 0.f};
        v4f o[8];
#pragma unroll
        for (int f = 0; f < 8; f++) o[f] = zero;
#pragma unroll
        for (int r = 0; r < 4; r++) { m_r[r] = -1e30f; l_r[r] = 0.f; }

        int ntiles = 2 * qt + 2;
        for (int t = 0; t < ntiles; t++) {
            int j0 = t * 32;
            __syncthreads();
#pragma unroll
            for (int i = 0; i < 2; i++) {  // stage 32 keys x 128 feats
                int ch = tid + i * 256;
                int key = ch >> 4, f8 = ch & 15;
                size_t gidx = ((size_t)(j0 + key) * NKV + kvh) * HD + f8 * 8;
                *(uint4*)&Ks[kswz(key, f8 * 8)] = *(const uint4*)&K[gidx];
                v8bf vv = *(const v8bf*)&V[gidx];
#pragma unroll
                for (int j = 0; j < 8; j++) {
                    int feat = f8 * 8 + j;
                    Vt[feat * 64 + (key ^ vswz(feat))] = vv[j];
                }
            }
            __syncthreads();
            v4f s0 = zero, s1 = zero;
            __builtin_amdgcn_s_setprio(1);
#pragma unroll
            for (int kk = 0; kk < 4; kk++) {
                v8bf k0f = *(const v8bf*)&Ks[kswz(c, kk * 32 + g * 8)];
                v8bf k1f = *(const v8bf*)&Ks[kswz(16 + c, kk * 32 + g * 8)];
                s0 = mfma16(qf[kk], k0f, s0);
                s1 = mfma16(qf[kk], k1f, s1);
            }
            __builtin_amdgcn_s_setprio(0);
            float p0[4], p1[4];
#pragma unroll
            for (int r = 0; r < 4; r++) {
                int row = rowbase + g * 4 + r;
                float a = s0[r] * scale, b = s1[r] * scale;
                if (j0 + c > row) a = -1e30f;
                if (j0 + 16 + c > row) b = -1e30f;
                float v = fmaxf(a, b);
                v = fmaxf(v, __shfl_xor(v, 1));
                v = fmaxf(v, __shfl_xor(v, 2));
                v = fmaxf(v, __shfl_xor(v, 4));
                v = fmaxf(v, __shfl_xor(v, 8));
                float mn = fmaxf(m_r[r], v);
                float al = __expf(m_r[r] - mn);
                float e0 = __expf(a - mn), e1 = __expf(b - mn);
                float srow = e0 + e1;
                srow += __shfl_xor(srow, 1);
                srow += __shfl_xor(srow, 2);
                srow += __shfl_xor(srow, 4);
                srow += __shfl_xor(srow, 8);
                l_r[r] = al * l_r[r] + srow;
                m_r[r] = mn;
                alpha[r] = al;
                p0[r] = e0; p1[r] = e1;
            }
#pragma unroll
            for (int f = 0; f < 8; f++)
#pragma unroll
                for (int r = 0; r < 4; r++) o[f][r] *= alpha[r];
#pragma unroll
            for (int r = 0; r < 4; r++) {
                Pl[w][g * 4 + r][c] = (__bf16)p0[r];
                Pl[w][g * 4 + r][16 + c] = (__bf16)p1[r];
            }
            __syncthreads();
            v8bf pf = *(const v8bf*)&Pl[w][c][g * 8];
            __builtin_amdgcn_s_setprio(1);
#pragma unroll
            for (int f = 0; f < 8; f++) {
                int feat = f * 16 + c;
                v8bf vf = *(const v8bf*)&Vt[feat * 64 + ((g * 8) ^ vswz(feat))];
                o[f] = mfma16(pf, vf, o[f]);
            }
            __builtin_amdgcn_s_setprio(0);
        }
#pragma unroll
        for (int f = 0; f < 8; f++)
#pragma unroll
            for (int r = 0; r < 4; r++) {
                float val = o[f][r] / l_r[r];
                O[((size_t)(rowbase + g * 4 + r) * NH + h) * HD + f * 16 + c] = (__bf16)val;
            }
    }
}

extern "C" void kernel_launch(void* const* d_in, const int* in_sizes, int n_in,
                              void* d_out, int out_size, void* d_ws, size_t ws_size,
                              hipStream_t stream)
{
    const float* x   = (const float*)d_in[0];
    const float* wq  = (const float*)d_in[2];
    const float* bq  = (const float*)d_in[3];
    const float* wk  = (const float*)d_in[4];
    const float* bk  = (const float*)d_in[5];
    const float* wv  = (const float*)d_in[6];
    const float* bv  = (const float*)d_in[7];
    const float* wo  = (const float*)d_in[8];
    const float* wg  = (const float*)d_in[9];
    const float* wu  = (const float*)d_in[10];
    const float* wd  = (const float*)d_in[11];
    const float* ln1 = (const float*)d_in[12];
    const float* ln2 = (const float*)d_in[13];
    const int* sidx  = (const int*)d_in[14];
    float* out = (float*)d_out;

    char* ws = (char*)d_ws;
    const size_t MB = 1ull << 20;
    // activations (both paths)
    __bf16* h_in = (__bf16*)(ws + 0 * MB);    // 16 MB
    __bf16* q_b  = (__bf16*)(ws + 16 * MB);   // 16 MB
    __bf16* k_b  = (__bf16*)(ws + 32 * MB);   // 4 MB
    __bf16* v_b  = (__bf16*)(ws + 36 * MB);   // 4 MB
    __bf16* ao   = (__bf16*)(ws + 40 * MB);   // 16 MB
    __bf16* h2   = (__bf16*)(ws + 56 * MB);   // 16 MB
    __bf16* gate = (__bf16*)(ws + 72 * MB);   // 56 MB
    __bf16* mid  = (__bf16*)(ws + 128 * MB);  // 56 MB -> 184 MB

    bool big = ws_size >= 600 * MB;

    if (big) {
        // bf16 weight mirrors
        __bf16* wq_b = (__bf16*)(ws + 184 * MB);  // 32
        __bf16* wk_b = (__bf16*)(ws + 216 * MB);  // 8
        __bf16* wv_b = (__bf16*)(ws + 224 * MB);  // 8
        __bf16* wo_b = (__bf16*)(ws + 232 * MB);  // 32
        __bf16* wg_b = (__bf16*)(ws + 264 * MB);  // 112
        __bf16* wu_b = (__bf16*)(ws + 376 * MB);  // 112
        __bf16* wd_b = (__bf16*)(ws + 488 * MB);  // 112 -> 600 MB

        f32_to_bf16<<<2048, 256, 0, stream>>>(wq, wq_b, (D_DIM * D_DIM) / 4);
        f32_to_bf16<<<2048, 256, 0, stream>>>(wk, wk_b, (1024 * D_DIM) / 4);
        f32_to_bf16<<<2048, 256, 0, stream>>>(wv, wv_b, (1024 * D_DIM) / 4);
        f32_to_bf16<<<2048, 256, 0, stream>>>(wo, wo_b, (D_DIM * D_DIM) / 4);
        f32_to_bf16<<<2048, 256, 0, stream>>>(wg, wg_b, (14336 * D_DIM) / 4);
        f32_to_bf16<<<2048, 256, 0, stream>>>(wu, wu_b, (14336 * D_DIM) / 4);
        f32_to_bf16<<<2048, 256, 0, stream>>>(wd, wd_b, (D_DIM * 14336) / 4);

        rmsnorm_bf16<<<S_LEN, 256, 0, stream>>>(x, ln1, h_in);
        gemm_bt<__bf16, true, true, false, false><<<dim3(32, 16), 256, 0, stream>>>(h_in, wq_b, bq, nullptr, nullptr, q_b, 4096, 4096);
        gemm_bt<__bf16, true, true, false, false><<<dim3(8, 16), 256, 0, stream>>>(h_in, wk_b, bk, nullptr, nullptr, k_b, 1024, 4096);
        gemm_bt<__bf16, true, true, false, false><<<dim3(8, 16), 256, 0, stream>>>(h_in, wv_b, bv, nullptr, nullptr, v_b, 1024, 4096);
        rope_inplace<<<S_LEN, 256, 0, stream>>>(q_b, k_b, sidx);
        flash_attn<<<dim3(S_LEN / 128, NH), 256, 0, stream>>>(q_b, k_b, v_b, ao);
        gemm_bt<float, true, false, true, false><<<dim3(32, 16), 256, 0, stream>>>(ao, wo_b, nullptr, x, nullptr, out, 4096, 4096);
        rmsnorm_bf16<<<S_LEN, 256, 0, stream>>>(out, ln2, h2);
        gemm_bt<__bf16, true, false, false, false><<<dim3(112, 16), 256, 0, stream>>>(h2, wg_b, nullptr, nullptr, nullptr, gate, 14336, 4096);
        gemm_bt<__bf16, true, false, false, true><<<dim3(112, 16), 256, 0, stream>>>(h2, wu_b, nullptr, nullptr, gate, mid, 14336, 4096);
        gemm_bt<float, true, false, true, false><<<dim3(32, 16), 256, 0, stream>>>(mid, wd_b, nullptr, out, nullptr, out, 4096, 14336);
    } else {
        // fallback: fp32-W reg-staged (swizzled) path, no weight mirrors
        rmsnorm_bf16<<<S_LEN, 256, 0, stream>>>(x, ln1, h_in);
        gemm_bt<__bf16, false, true, false, false><<<dim3(32, 16), 256, 0, stream>>>(h_in, wq, bq, nullptr, nullptr, q_b, 4096, 4096);
        gemm_bt<__bf16, false, true, false, false><<<dim3(8, 16), 256, 0, stream>>>(h_in, wk, bk, nullptr, nullptr, k_b, 1024, 4096);
        gemm_bt<__bf16, false, true, false, false><<<dim3(8, 16), 256, 0, stream>>>(h_in, wv, bv, nullptr, nullptr, v_b, 1024, 4096);
        rope_inplace<<<S_LEN, 256, 0, stream>>>(q_b, k_b, sidx);
        flash_attn<<<dim3(S_LEN / 128, NH), 256, 0, stream>>>(q_b, k_b, v_b, ao);
        gemm_bt<float, false, false, true, false><<<dim3(32, 16), 256, 0, stream>>>(ao, wo, nullptr, x, nullptr, out, 4096, 4096);
        rmsnorm_bf16<<<S_LEN, 256, 0, stream>>>(out, ln2, h2);
        gemm_bt<__bf16, false, false, false, false><<<dim3(112, 16), 256, 0, stream>>>(h2, wg, nullptr, nullptr, nullptr, gate, 14336, 4096);
        gemm_bt<__bf16, false, false, false, true><<<dim3(112, 16), 256, 0, stream>>>(h2, wu, nullptr, nullptr, gate, mid, 14336, 4096);
        gemm_bt<float, false, false, true, false><<<dim3(32, 16), 256, 0, stream>>>(mid, wd, nullptr, out, nullptr, out, 4096, 14336);
    }
}